// Round 7
// baseline (742.871 us; speedup 1.0000x reference)
//
#include <hip/hip_runtime.h>
#include <hip/hip_bf16.h>

#define B_ 16
#define S_ 4096
#define E_ 768
#define H_ 4
#define A_ 128

constexpr float ALPHA = 0.2f;
constexpr float LOG2E = 1.44269504088896340736f;

typedef __attribute__((ext_vector_type(4))) float f32x4;
typedef __attribute__((ext_vector_type(8))) short bf16x8;

__device__ __forceinline__ unsigned short f2bf(float f) {
    union { float f; unsigned int u; } v;
    v.f = f;
    unsigned int u = v.u;
    unsigned int r = (u + 0x7FFFu + ((u >> 16) & 1u)) >> 16;
    return (unsigned short)r;
}

__device__ __forceinline__ unsigned int pk2bf(float lo, float hi) {
    // compiles to v_cvt_pk_bf16_f32 (1 instr / 2 elems)
    __hip_bfloat162 h2 = __float22bfloat162_rn(make_float2(lo, hi));
    union { __hip_bfloat162 h; unsigned int u; } c;
    c.h = h2;
    return c.u;
}

__device__ __forceinline__ bf16x8 cvt8(const f32x4 a, const f32x4 b) {
    union { unsigned int u[4]; bf16x8 v; } r;
    r.u[0] = pk2bf(a[0], a[1]);
    r.u[1] = pk2bf(a[2], a[3]);
    r.u[2] = pk2bf(b[0], b[1]);
    r.u[3] = pk2bf(b[2], b[3]);
    return r.v;
}

// ---------------------------------------------------------------------------
// prep1: W1 [h][e][a] f32 -> W1T [h][a][e] bf16
// ---------------------------------------------------------------------------
__global__ __launch_bounds__(256) void k_prep1(const float* __restrict__ w1,
                                               unsigned short* __restrict__ w1t) {
    __shared__ unsigned short t[64 * 65];
    int bid = blockIdx.x;              // 96 = 4h * 12e * 2a
    int ta = bid & 1;
    int te = (bid >> 1) % 12;
    int h  = bid / 24;
    const float* src = w1 + (size_t)h * E_ * A_;
    unsigned short* dst = w1t + (size_t)h * A_ * E_;
    int tid = threadIdx.x;
#pragma unroll
    for (int it = 0; it < 16; ++it) {
        int idx = it * 256 + tid;
        int r = idx >> 6, c = idx & 63;
        t[r * 65 + c] = f2bf(src[(size_t)(te * 64 + r) * A_ + ta * 64 + c]);
    }
    __syncthreads();
#pragma unroll
    for (int it = 0; it < 16; ++it) {
        int idx = it * 256 + tid;
        int a = idx >> 6, e = idx & 63;
        dst[(size_t)(ta * 64 + a) * E_ + te * 64 + e] = t[e * 65 + a];
    }
}

// ---------------------------------------------------------------------------
// prep2: W2 [h][a][e] f32 -> W2T [h][e][a] bf16, pre-scaled by log2(e).
// b2 dropped: constant over s => cancels in softmax over s.
// ---------------------------------------------------------------------------
__global__ __launch_bounds__(256) void k_prep2(const float* __restrict__ w2,
                                               unsigned short* __restrict__ w2t) {
    __shared__ unsigned short t[64 * 65];
    int bid = blockIdx.x;              // 96
    int te = bid % 12;
    int ta = (bid / 12) & 1;
    int h  = bid / 24;
    const float* src = w2 + (size_t)h * A_ * E_;
    unsigned short* dst = w2t + (size_t)h * E_ * A_;
    int tid = threadIdx.x;
#pragma unroll
    for (int it = 0; it < 16; ++it) {
        int idx = it * 256 + tid;
        int r = idx >> 6, c = idx & 63;
        t[r * 65 + c] = f2bf(src[(size_t)(ta * 64 + r) * E_ + te * 64 + c] * LOG2E);
    }
    __syncthreads();
#pragma unroll
    for (int it = 0; it < 16; ++it) {
        int idx = it * 256 + tid;
        int e = idx >> 6, a = idx & 63;
        dst[(size_t)(te * 64 + e) * A_ + ta * 64 + a] = t[a * 65 + e];
    }
}

// ---------------------------------------------------------------------------
// stage1 (barrier-free, LDS-free): Hm[b,h,s,a] = bf16(leakyrelu(x W1 + b1))
// 512 thr / 8 waves; block tile 128s x 128a; wave tile 32s x 64a
// (sw = wv&3 selects 32-s quarter, aw = wv>>2 selects 64-a half).
// BK=32; A-frags (W1T, L2-resident) and B-frags (x, f32->bf16 inline)
// loaded DIRECTLY from global; 2-deep ping-pong register prefetch;
// zero __syncthreads in the K-loop.
// ---------------------------------------------------------------------------
__global__ __launch_bounds__(512, 4) void k_stage1(
    const float* __restrict__ x, const unsigned short* __restrict__ w1t,
    const float* __restrict__ b1, unsigned short* __restrict__ hm) {

    int bid = blockIdx.x;
    int wid = (bid & 7) * 256 + (bid >> 3);   // bijective: 2048 = 8*256
    const int h  = wid & 3;
    const int st = (wid >> 2) & 31;
    const int b  = wid >> 7;
    const int s0 = st * 128;

    const int tid = threadIdx.x;
    const int wv = tid >> 6, lane = tid & 63;
    const int lr = lane & 15, lg = lane >> 4;
    const int sw = wv & 3;      // s quarter (32 rows)
    const int aw = wv >> 2;     // a half (64 cols)

    // per-lane base pointers (k-offset lg*8 folded in)
    const float* xrow = x + ((size_t)b * S_ + s0 + sw * 32 + lr) * E_ + lg * 8;
    const unsigned short* wrow = w1t + ((size_t)h * A_ + aw * 64 + lr) * E_ + lg * 8;
    // row strides for sf / nf steps: 16 rows * 768 = 12288 elements

    f32x4 acc[2][4];
#pragma unroll
    for (int i = 0; i < 2; ++i)
#pragma unroll
        for (int j = 0; j < 4; ++j) acc[i][j] = (f32x4)0.0f;

    bf16x8 wA[4], wB[4];
    f32x4  xA[2][2], xB[2][2];

#define S1_LOADS(WB_, XB_, K0_)                                              \
    {                                                                        \
        const int k_ = (K0_);                                                \
        _Pragma("unroll")                                                    \
        for (int nf = 0; nf < 4; ++nf)                                       \
            WB_[nf] = *(const bf16x8*)(wrow + nf * 12288 + k_);              \
        _Pragma("unroll")                                                    \
        for (int sf = 0; sf < 2; ++sf) {                                     \
            XB_[sf][0] = *(const f32x4*)(xrow + sf * 12288 + k_);            \
            XB_[sf][1] = *(const f32x4*)(xrow + sf * 12288 + k_ + 4);        \
        }                                                                    \
    }

#define S1_COMPUTE(WB_, XB_)                                                 \
    {                                                                        \
        bf16x8 xb0 = cvt8(XB_[0][0], XB_[0][1]);                             \
        bf16x8 xb1 = cvt8(XB_[1][0], XB_[1][1]);                             \
        _Pragma("unroll")                                                    \
        for (int nf = 0; nf < 4; ++nf) {                                     \
            acc[0][nf] = __builtin_amdgcn_mfma_f32_16x16x32_bf16(            \
                WB_[nf], xb0, acc[0][nf], 0, 0, 0);                          \
            acc[1][nf] = __builtin_amdgcn_mfma_f32_16x16x32_bf16(            \
                WB_[nf], xb1, acc[1][nf], 0, 0, 0);                          \
        }                                                                    \
    }

    S1_LOADS(wA, xA, 0)
#pragma unroll 1
    for (int ks = 0; ks < 24; ks += 2) {
        if (ks + 1 < 24) S1_LOADS(wB, xB, (ks + 1) * 32)
        S1_COMPUTE(wA, xA)
        if (ks + 2 < 24) S1_LOADS(wA, xA, (ks + 2) * 32)
        S1_COMPUTE(wB, xB)
    }
#undef S1_LOADS
#undef S1_COMPUTE

    // epilogue: C[row = a-offset = lg*4+j, col = s-offset = lr]
    // pack 4 a-contiguous bf16 -> 8B store
    const size_t hb = ((size_t)(b * H_ + h) * S_ + s0 + sw * 32) * A_ + aw * 64;
#pragma unroll
    for (int nf = 0; nf < 4; ++nf) {
        f32x4 bv = *(const f32x4*)(b1 + h * A_ + aw * 64 + nf * 16 + lg * 4);
#pragma unroll
        for (int sf = 0; sf < 2; ++sf) {
            f32x4 v = acc[sf][nf] + bv;
#pragma unroll
            for (int j = 0; j < 4; ++j) v[j] = v[j] >= 0.0f ? v[j] : ALPHA * v[j];
            uint2 p;
            p.x = pk2bf(v[0], v[1]);
            p.y = pk2bf(v[2], v[3]);
            *(uint2*)(hm + hb + (size_t)(sf * 16 + lr) * A_ + nf * 16 + lg * 4) = p;
        }
    }
}

// ---------------------------------------------------------------------------
// stage2: per block (b, h, 128-s chunk): hm tile -> LDS once (swizzled);
// et loop (6 x 128 e): W2 frags in regs; barrier-free streaming inner loop:
// 4 LDS reads + 8 MFMA + 8 exp2 + x f32x4 loads; per-et shuffle-reduce
// over the 16 s-columns; write (z,o) partials.
// ---------------------------------------------------------------------------
__global__ __launch_bounds__(256, 4) void k_stage2(
    const float* __restrict__ x, const unsigned short* __restrict__ hm,
    const unsigned short* __restrict__ w2t,
    float* __restrict__ part_z, float* __restrict__ part_o) {

    int bid = blockIdx.x;
    int wid = (bid & 7) * 256 + (bid >> 3);
    const int h  = wid & 3;
    const int sc = (wid >> 2) & 31;
    const int b  = wid >> 7;
    const int s0 = sc * 128;

    const int tid = threadIdx.x;
    const int wv = tid >> 6, lane = tid & 63;
    const int lr = lane & 15, lg = lane >> 4;

    __shared__ unsigned short hmt[128 * 128];  // [s][a] bf16, swizzled, 32KB

    // one-time staging of the hm tile
    {
        const unsigned short* hp = hm + ((size_t)(b * H_ + h) * S_ + s0) * A_;
        int r = tid >> 1;
        int c = tid & 1;
#pragma unroll
        for (int l = 0; l < 8; ++l) {
            int ch = c * 8 + l;
            bf16x8 v = *(const bf16x8*)(hp + (size_t)r * A_ + ch * 8);
            int byte = (r * 256 + ch * 16) ^ ((r & 7) << 4);
            *(bf16x8*)((char*)hmt + byte) = v;
        }
    }
    __syncthreads();

    const float* xb = x + ((size_t)b * S_ + s0) * E_;
    const unsigned short* w2h = w2t + (size_t)h * E_ * A_;
    const size_t pbase = (size_t)(b * H_ + h) * E_ * 32 + sc;

#pragma unroll 1
    for (int et = 0; et < 6; ++et) {
        const int e0 = et * 128 + wv * 32;     // this wave's 32-e slice
        bf16x8 w2f[2][4];
#pragma unroll
        for (int nf = 0; nf < 2; ++nf) {
            const unsigned short* q = w2h + (size_t)(e0 + nf * 16 + lr) * A_ + lg * 8;
#pragma unroll
            for (int k4 = 0; k4 < 4; ++k4) w2f[nf][k4] = *(const bf16x8*)(q + k4 * 32);
        }
        f32x4 zz[2], oo[2];
#pragma unroll
        for (int nf = 0; nf < 2; ++nf) { zz[nf] = (f32x4)0.0f; oo[nf] = (f32x4)0.0f; }

#pragma unroll 2
        for (int itr = 0; itr < 8; ++itr) {
            int srow = itr * 16 + lr;
            bf16x8 hf[4];
#pragma unroll
            for (int k4 = 0; k4 < 4; ++k4)
                hf[k4] = *(const bf16x8*)((char*)hmt +
                          ((srow * 256 + (k4 * 32 + lg * 8) * 2) ^ ((srow & 7) << 4)));
            f32x4 lac[2];
            lac[0] = (f32x4)0.0f; lac[1] = (f32x4)0.0f;
#pragma unroll
            for (int k4 = 0; k4 < 4; ++k4) {
                lac[0] = __builtin_amdgcn_mfma_f32_16x16x32_bf16(w2f[0][k4], hf[k4], lac[0], 0, 0, 0);
                lac[1] = __builtin_amdgcn_mfma_f32_16x16x32_bf16(w2f[1][k4], hf[k4], lac[1], 0, 0, 0);
            }
            // C: col(s)=lr, row(e)=lg*4+j ; logits already in log2 domain
#pragma unroll
            for (int nf = 0; nf < 2; ++nf) {
                const float* xq = xb + (size_t)srow * E_ + e0 + nf * 16 + lg * 4;
                f32x4 xv = *(const f32x4*)xq;
                f32x4 pv;
#pragma unroll
                for (int j = 0; j < 4; ++j) pv[j] = exp2f(lac[nf][j]);
                zz[nf] += pv;
                oo[nf] += pv * xv;
            }
        }
        // reduce the 16 s-columns (lr lanes within each lg group)
#pragma unroll
        for (int nf = 0; nf < 2; ++nf)
#pragma unroll
            for (int j = 0; j < 4; ++j) {
                float zv = zz[nf][j], ov = oo[nf][j];
#pragma unroll
                for (int msk = 1; msk < 16; msk <<= 1) {
                    zv += __shfl_xor(zv, msk);
                    ov += __shfl_xor(ov, msk);
                }
                if (lr == 0) {
                    int e = e0 + nf * 16 + lg * 4 + j;
                    part_z[pbase + (size_t)e * 32] = zv;
                    part_o[pbase + (size_t)e * 32] = ov;
                }
            }
    }
}

// ---------------------------------------------------------------------------
// merge: out[b,h,e] = sum_sc o / sum_sc z  (32 contiguous partials each)
// ---------------------------------------------------------------------------
__global__ __launch_bounds__(256) void k_merge(const float* __restrict__ part_z,
                                               const float* __restrict__ part_o,
                                               float* __restrict__ out) {
    int idx = blockIdx.x * 256 + threadIdx.x;
    if (idx >= B_ * H_ * E_) return;
    const float* pz = part_z + (size_t)idx * 32;
    const float* po = part_o + (size_t)idx * 32;
    float z = 0.f, o = 0.f;
#pragma unroll
    for (int q = 0; q < 8; ++q) {
        f32x4 a = *(const f32x4*)(pz + q * 4);
        f32x4 c = *(const f32x4*)(po + q * 4);
        z += (a[0] + a[1]) + (a[2] + a[3]);
        o += (c[0] + c[1]) + (c[2] + c[3]);
    }
    out[idx] = o / z;
}

// ---------------------------------------------------------------------------
extern "C" void kernel_launch(void* const* d_in, const int* in_sizes, int n_in,
                              void* d_out, int out_size, void* d_ws, size_t ws_size,
                              hipStream_t stream) {
    const float* x  = (const float*)d_in[0];
    const float* w1 = (const float*)d_in[1];
    const float* b1 = (const float*)d_in[2];
    const float* w2 = (const float*)d_in[3];
    // d_in[4] (b2) unused: constant over s, cancels in softmax
    float* out = (float*)d_out;

    char* ws = (char*)d_ws;
    unsigned short* hmw    = (unsigned short*)ws;                 // 67,108,864 B
    unsigned short* w1t    = (unsigned short*)(ws + 67108864);    //    786,432 B
    unsigned short* w2t    = (unsigned short*)(ws + 67895296);    //    786,432 B
    float*          part_z = (float*)(ws + 68681728);             //  6,291,456 B
    float*          part_o = (float*)(ws + 74973184);             //  6,291,456 B

    k_prep1 <<<dim3(96),   256, 0, stream>>>(w1, w1t);
    k_prep2 <<<dim3(96),   256, 0, stream>>>(w2, w2t);
    k_stage1<<<dim3(2048), 512, 0, stream>>>(x, w1t, b1, hmw);
    k_stage2<<<dim3(2048), 256, 0, stream>>>(x, hmw, w2t, part_z, part_o);
    k_merge <<<dim3(192),  256, 0, stream>>>(part_z, part_o, out);
}